// Round 1
// baseline (81608.411 us; speedup 1.0000x reference)
//
#include <hip/hip_runtime.h>
#include <math.h>

// ESN recurrence: x_t = tanh(w_in * u_t + W @ x_{t-1}), out[t-washout] = c . x_t
// Strategy: persistent cooperative kernel, W resident in VGPRs (64 regs/thread),
// per-step grid barrier (8 spread counters, release/acquire agent fences),
// double-buffered x in workspace.

#define H_ 2048
#define ROWS_PER_BLOCK 8   // H / 256 blocks
// ws float layout: [0,2048)=xbuf0  [2048,4096)=xbuf1  [4096,6144)=c  [6144,6400)=counters(uint)

__global__ __launch_bounds__(1024) void esn_init(const int* __restrict__ mask,
                                                 const float* __restrict__ w_out,
                                                 float* __restrict__ ws_f,
                                                 float* __restrict__ out,
                                                 int out_size, int H)
{
    // single block
    int tid = threadIdx.x;
    for (int i = tid; i < 6656; i += blockDim.x) ws_f[i] = 0.0f;
    for (int i = tid; i < out_size; i += blockDim.x) out[i] = 0.0f;
    __syncthreads();
    float* c = ws_f + 2 * H;   // readout coefficient vector
    for (int i = tid; i < H; i += blockDim.x) atomicAdd(&c[mask[i]], w_out[i]);
}

__global__ __launch_bounds__(256) void esn_run(const float* __restrict__ u,
                                               const float* __restrict__ w_res,
                                               const float* __restrict__ w_in,
                                               float* __restrict__ out,
                                               float* __restrict__ ws_f,
                                               int T, int washout)
{
    const int tid  = threadIdx.x;
    const int wave = tid >> 6;
    const int lane = tid & 63;
    const int r    = lane >> 3;       // row within block (0..7)
    const int m    = lane & 7;        // octet position -> 64-elem j chunk
    const int row  = blockIdx.x * ROWS_PER_BLOCK + r;
    const int jbase = wave * 512 + m * 64;   // this lane's j window start

    // ---- one-time: load this lane's 64 weights into VGPRs ----
    float4 wreg[16];
    {
        const float4* wr4 = (const float4*)(w_res + (size_t)row * H_ + jbase);
#pragma unroll
        for (int i = 0; i < 16; ++i) wreg[i] = wr4[i];
    }

    float win_r = 0.0f, c_r = 0.0f;
    if (wave == 0 && lane < 8) {
        int myrow = blockIdx.x * ROWS_PER_BLOCK + lane;
        win_r = w_in[myrow];
        c_r   = (ws_f + 2 * H_)[myrow];
    }

    float* buf0 = ws_f;
    float* buf1 = ws_f + H_;
    unsigned* counters = (unsigned*)(ws_f + 3 * H_);
    unsigned* mycnt = counters + (blockIdx.x & 7) * 32;  // 8 counters, 128B apart

    __shared__ float part[32];

    int broken = 0;   // failsafe: never hang the GPU

    for (int k = 0; k < T; ++k) {
        const float* xsrc = (k & 1) ? buf1 : buf0;
        float*       xdst = (k & 1) ? buf0 : buf1;
        const float4* xb = (const float4*)xsrc + (jbase >> 2);

        float uk = 0.0f;
        if (wave == 0) uk = u[k];   // overlaps with the dot-product loads

        // ---- partial dot: this lane's 64 j's of its row ----
        float4 a; a.x = 0.f; a.y = 0.f; a.z = 0.f; a.w = 0.f;
#pragma unroll
        for (int i = 0; i < 16; ++i) {
            float4 xv = xb[i];
            a.x = fmaf(wreg[i].x, xv.x, a.x);
            a.y = fmaf(wreg[i].y, xv.y, a.y);
            a.z = fmaf(wreg[i].z, xv.z, a.z);
            a.w = fmaf(wreg[i].w, xv.w, a.w);
        }
        float acc = (a.x + a.y) + (a.z + a.w);
        // reduce across the 8 octet lanes of this row (bits 0..2 of lane)
        acc += __shfl_xor(acc, 1);
        acc += __shfl_xor(acc, 2);
        acc += __shfl_xor(acc, 4);
        if (m == 0) part[wave * 8 + r] = acc;
        __syncthreads();

        // ---- wave 0 finishes the 8 rows: cross-wave sum, tanh, store, readout ----
        if (wave == 0 && lane < 8) {
            float z = (part[lane] + part[8 + lane]) + (part[16 + lane] + part[24 + lane]);
            z = fmaf(win_r, uk, z);
            z = fminf(fmaxf(z, -15.0f), 15.0f);
            float e = __expf(2.0f * z);
            float t = (e - 1.0f) / (e + 1.0f);
            xdst[blockIdx.x * ROWS_PER_BLOCK + lane] = t;
            float p = c_r * t;
            p += __shfl_xor(p, 1);
            p += __shfl_xor(p, 2);
            p += __shfl_xor(p, 4);
            if (lane == 0 && k >= washout) atomicAdd(&out[k - washout], p);
        }
        __syncthreads();   // drains all waves' vmem (vmcnt 0 before s_barrier)

        // ---- grid barrier: release -> add -> poll 8 counters -> acquire ----
        if (wave == 0) {
            __builtin_amdgcn_fence(__ATOMIC_RELEASE, "agent");
            if (lane == 0)
                __hip_atomic_fetch_add(mycnt, 1u, __ATOMIC_RELAXED, __HIP_MEMORY_SCOPE_AGENT);
            unsigned target = (unsigned)(k + 1) * 32u;
            if (!broken) {
                int spins = 0;
                for (;;) {
                    unsigned v = target;
                    if (lane < 8)
                        v = __hip_atomic_load(counters + lane * 32, __ATOMIC_RELAXED,
                                              __HIP_MEMORY_SCOPE_AGENT);
                    if (__all(v >= target)) break;
                    if (++spins > 1000000) { broken = 1; break; }
                    __builtin_amdgcn_s_sleep(1);
                }
            }
            __builtin_amdgcn_fence(__ATOMIC_ACQUIRE, "agent");
        }
        __syncthreads();
    }
}

extern "C" void kernel_launch(void* const* d_in, const int* in_sizes, int n_in,
                              void* d_out, int out_size, void* d_ws, size_t ws_size,
                              hipStream_t stream)
{
    const float* u     = (const float*)d_in[0];
    const float* w_res = (const float*)d_in[1];
    const float* w_in  = (const float*)d_in[2];
    const float* w_out = (const float*)d_in[3];
    const int*   mask  = (const int*)d_in[4];
    int T = in_sizes[0];
    int H = in_sizes[2];
    int washout = T - out_size;
    float* out  = (float*)d_out;
    float* ws_f = (float*)d_ws;

    hipLaunchKernelGGL(esn_init, dim3(1), dim3(1024), 0, stream,
                       mask, w_out, ws_f, out, out_size, H);

    int nblocks = H / ROWS_PER_BLOCK;   // 256
    void* args[] = { (void*)&u, (void*)&w_res, (void*)&w_in,
                     (void*)&out, (void*)&ws_f, (void*)&T, (void*)&washout };
    hipError_t e = hipLaunchCooperativeKernel((const void*)esn_run,
                                              dim3(nblocks), dim3(256),
                                              args, 0, stream);
    if (e != hipSuccess) {
        // fallback: 256 blocks on 256 CUs are co-resident in practice
        hipLaunchKernelGGL(esn_run, dim3(nblocks), dim3(256), 0, stream,
                           u, w_res, w_in, out, ws_f, T, washout);
    }
}